// Round 2
// baseline (84.245 us; speedup 1.0000x reference)
//
#include <hip/hip_runtime.h>
#include <hip/hip_bf16.h>

// Problem constants
#define B_ROWS 65536
#define DIN    784
#define DHID   100
#define DOUT   10

#define NP     112                 // DHID padded to 7*16
#define NT     26                  // k-steps of 32 (832 = 26*32)
#define W1T_ELEMS (NT * 7 * 512)   // 93184 bf16, fragment-order layout
#define W2T_OFF   W1T_ELEMS        // w2t: [16][128] bf16 = 2048
#define TM     64                  // rows per block; grid = 1024

typedef float  f32x4  __attribute__((ext_vector_type(4)));
typedef __bf16 bf16x8 __attribute__((ext_vector_type(8)));

__device__ inline unsigned short f2bf(float f) {
    unsigned int u = __builtin_bit_cast(unsigned int, f);
    u = (u + 0x7fffu + ((u >> 16) & 1u)) >> 16;   // RNE
    return (unsigned short)u;
}

// ---- prep: build fragment-order W1T + W2T (bf16, zero-padded), seed freq_out.
// W1T layout: idx = ((t*7 + n)*64 + lane)*8 + j  holds
//   B[k = t*32 + (lane>>4)*8 + j][col = n*16 + (lane&15)]  (= W1[k][col])
// so the main loop's B-fragment load is wbuf + t*3584 + n*512 + lane*8 : 8 bf16,
// perfectly coalesced (1 KB/wave-instr), offsets imm-foldable.
__global__ void prep_kernel(const float* __restrict__ W1,
                            const float* __restrict__ W2,
                            const float* __restrict__ freq_in,
                            unsigned short* __restrict__ wbuf,
                            float* __restrict__ freq_out) {
    int idx = blockIdx.x * 256 + threadIdx.x;
    if (idx < W1T_ELEMS) {
        int s  = idx >> 9;          // fragment slot (t*7+n), 0..181
        int e  = idx & 511;
        int ln = e >> 3, j = e & 7;
        int n  = s % 7, t = s / 7;
        int k   = t * 32 + ((ln >> 4) << 3) + j;
        int col = n * 16 + (ln & 15);
        float v = (k < DIN && col < DHID) ? W1[k * DHID + col] : 0.f;
        wbuf[idx] = f2bf(v);
    } else if (idx < W1T_ELEMS + 2048) {
        int j2 = idx - W1T_ELEMS;
        int r  = j2 >> 7;           // 0..15 (output col)
        int k  = j2 & 127;          // 0..127 (h col)
        float v = (r < DOUT && k < DHID) ? W2[k * DOUT + r] : 0.f;
        wbuf[idx] = f2bf(v);
    }
    if (idx < DHID) freq_out[idx] = freq_in[idx];
}

__global__ __launch_bounds__(256, 4)
void fused_mlp2(const float* __restrict__ x,
                const unsigned short* __restrict__ wbuf,
                const float* __restrict__ b1,
                const float* __restrict__ b2,
                float* __restrict__ outp,
                float* __restrict__ freq_out) {
    __shared__ unsigned short hs[TM][128];   // bf16 h tile (cols 112..127 zeroed)
    __shared__ float logits[TM][16];
    __shared__ float freqs[NP];

    const int tid  = threadIdx.x;
    const int lane = tid & 63;
    const int wave = tid >> 6;       // 0..3, owns rows wave*16..+15
    const int r16  = lane & 15;
    const int q    = lane >> 4;      // 0..3

    if (tid < NP) freqs[tid] = 0.f;

    const float* xp = x + ((size_t)blockIdx.x * TM + wave * 16 + r16) * DIN;
    const unsigned short* wb = wbuf + lane * 8;

    // ---- GEMM1 main loop: no LDS, no barriers. A: global f32 -> bf16 regs.
    // B: pre-permuted fragment-order bf16, L1/L2-resident.
    f32x4 acc[7] = {};
    for (int t = 0; t < NT; ++t) {
        const int kk = t * 32 + q * 8;
        float4 a0 = make_float4(0.f, 0.f, 0.f, 0.f), a1 = a0;
        if (kk < DIN) {              // 784 % 8 == 0 -> vectors never straddle
            a0 = *(const float4*)(xp + kk);
            a1 = *(const float4*)(xp + kk + 4);
        }
        bf16x8 av;
        av[0] = (__bf16)a0.x; av[1] = (__bf16)a0.y;
        av[2] = (__bf16)a0.z; av[3] = (__bf16)a0.w;
        av[4] = (__bf16)a1.x; av[5] = (__bf16)a1.y;
        av[6] = (__bf16)a1.z; av[7] = (__bf16)a1.w;
        const unsigned short* wt = wb + t * (7 * 512);
        #pragma unroll
        for (int n = 0; n < 7; ++n) {
            bf16x8 bv = *(const bf16x8*)(wt + n * 512);
            acc[n] = __builtin_amdgcn_mfma_f32_16x16x32_bf16(av, bv, acc[n], 0, 0, 0);
        }
    }

    // ---- zero-pad hs k=112..127 (GEMM2 reads them; w2t is 0 there but LDS
    // garbage could be NaN -> NaN*0=NaN)
    {
        int r = tid >> 2, cc = (tid & 3) << 2;   // 4 ushorts = 8 B each
        uint2 z; z.x = 0; z.y = 0;
        *(uint2*)&hs[r][112 + cc] = z;
    }
    __syncthreads();   // freqs init + pad visible; nothing else outstanding

    // ---- bias + relu -> hs (bf16), freq count from registers
    const bool lastBlk = (blockIdx.x == gridDim.x - 1);
    #pragma unroll
    for (int n = 0; n < 7; ++n) {
        const int col = n * 16 + r16;
        const float bias = (col < DHID) ? b1[col] : 0.f;
        float cnt = 0.f;
        #pragma unroll
        for (int i = 0; i < 4; ++i) {
            float v = acc[n][i] + bias;
            v = v > 0.f ? v : 0.f;
            union { __bf16 h; unsigned short u; } cv;
            cv.h = (__bf16)v;
            hs[wave * 16 + q * 4 + i][col] = cv.u;
            // reference skips the globally-last row (65535)
            bool excl = lastBlk && (wave == 3) && (q == 3) && (i == 3);
            cnt += (v > 0.f && !excl) ? 1.f : 0.f;
        }
        cnt += __shfl_xor(cnt, 16);   // reduce over q (lane = q*16 + r16)
        cnt += __shfl_xor(cnt, 32);
        if (q == 0) atomicAdd(&freqs[col], cnt);
    }
    __syncthreads();
    if (tid < DHID) atomicAdd(freq_out + tid, freqs[tid]);  // integer-valued f32: exact

    // ---- GEMM2 via MFMA: logits[64][16] = hs[64][128] @ w2t^T, K=128
    f32x4 acc2 = {};
    const unsigned short* w2t = wbuf + W2T_OFF;
    #pragma unroll
    for (int ks = 0; ks < 4; ++ks) {
        bf16x8 a2  = *(const bf16x8*)&hs[wave * 16 + r16][ks * 32 + q * 8];
        bf16x8 bv2 = *(const bf16x8*)(w2t + r16 * 128 + ks * 32 + q * 8);
        acc2 = __builtin_amdgcn_mfma_f32_16x16x32_bf16(a2, bv2, acc2, 0, 0, 0);
    }
    const float bias2 = (r16 < DOUT) ? b2[r16] : 0.f;
    #pragma unroll
    for (int i = 0; i < 4; ++i)
        logits[wave * 16 + q * 4 + i][r16] = acc2[i] + bias2;
    __syncthreads();

    // ---- softmax: one thread per row (10-wide)
    if (tid < TM) {
        float lg[DOUT];
        #pragma unroll
        for (int k = 0; k < DOUT; ++k) lg[k] = logits[tid][k];
        float mx = lg[0];
        #pragma unroll
        for (int k = 1; k < DOUT; ++k) mx = fmaxf(mx, lg[k]);
        float s = 0.f;
        #pragma unroll
        for (int k = 0; k < DOUT; ++k) { lg[k] = __expf(lg[k] - mx); s += lg[k]; }
        float inv = 1.f / s;
        float* o = outp + ((size_t)blockIdx.x * TM + tid) * DOUT;
        #pragma unroll
        for (int k = 0; k < DOUT; ++k) o[k] = lg[k] * inv;
    }
}

extern "C" void kernel_launch(void* const* d_in, const int* in_sizes, int n_in,
                              void* d_out, int out_size, void* d_ws, size_t ws_size,
                              hipStream_t stream) {
    const float* x    = (const float*)d_in[0];
    const float* W1   = (const float*)d_in[1];
    const float* b1   = (const float*)d_in[2];
    const float* freq = (const float*)d_in[3];
    const float* W2   = (const float*)d_in[4];
    const float* b2   = (const float*)d_in[5];
    float* outp     = (float*)d_out;
    float* freq_out = outp + (size_t)B_ROWS * DOUT;
    unsigned short* wbuf = (unsigned short*)d_ws;   // 93184+2048 bf16 = 190,464 B

    prep_kernel<<<(W1T_ELEMS + 2048) / 256, 256, 0, stream>>>(W1, W2, freq, wbuf, freq_out);
    fused_mlp2<<<B_ROWS / TM, 256, 0, stream>>>(x, wbuf, b1, b2, outp, freq_out);
}

// Round 4
// 58.640 us; speedup vs baseline: 1.4366x; 1.4366x over previous
//
#include <hip/hip_runtime.h>
#include <hip/hip_bf16.h>

// Problem constants
#define B_ROWS 65536
#define DIN    784
#define DHID   100
#define DOUT   10

#define NP     112                 // DHID padded to 7*16
#define NT     25                  // k-steps of 32 (800 >= 784)
#define W1T_ELEMS (NT * 7 * 512)   // 89600 bf16, fragment-order layout
#define W2T_OFF   W1T_ELEMS        // w2t: [16][128] bf16 = 2048
#define WBUF_ELEMS (W1T_ELEMS + 2048)
#define PART_OFF  ((((WBUF_ELEMS * 2) + 255) & ~255))   // byte offset of freq partials in ws
#define TM     64                  // rows per block
#define GRID1  (B_ROWS / TM)       // 1024

typedef float  f32x4  __attribute__((ext_vector_type(4)));
typedef __bf16 bf16x8 __attribute__((ext_vector_type(8)));

__device__ inline unsigned short f2bf(float f) {
    unsigned int u = __builtin_bit_cast(unsigned int, f);
    u = (u + 0x7fffu + ((u >> 16) & 1u)) >> 16;   // RNE
    return (unsigned short)u;
}

// ---- prep: build fragment-order W1T + W2T (bf16, zero-padded).
// W1T: idx = ((t*7+n)*64 + lane)*8 + j holds W1[k = t*32+(lane>>4)*8+j][col = n*16+(lane&15)]
// -> main-loop B-fragment load = wbuf + t*3584 + n*512 + lane*8, fully coalesced.
__global__ void prep_kernel(const float* __restrict__ W1,
                            const float* __restrict__ W2,
                            unsigned short* __restrict__ wbuf) {
    int idx = blockIdx.x * 256 + threadIdx.x;
    if (idx < W1T_ELEMS) {
        int s  = idx >> 9;          // fragment slot (t*7+n)
        int e  = idx & 511;
        int ln = e >> 3, j = e & 7;
        int n  = s % 7, t = s / 7;
        int k   = t * 32 + ((ln >> 4) << 3) + j;
        int col = n * 16 + (ln & 15);
        float v = (k < DIN && col < DHID) ? W1[k * DHID + col] : 0.f;
        wbuf[idx] = f2bf(v);
    } else if (idx < WBUF_ELEMS) {
        int j2 = idx - W1T_ELEMS;
        int r  = j2 >> 7;           // 0..15 (output col)
        int k  = j2 & 127;          // 0..127 (h col)
        float v = (r < DOUT && k < DHID) ? W2[k * DOUT + r] : 0.f;
        wbuf[idx] = f2bf(v);
    }
}

__global__ __launch_bounds__(256, 4)
void fused_mlp3(const float* __restrict__ x,
                const unsigned short* __restrict__ wbuf,
                const float* __restrict__ b1,
                const float* __restrict__ b2,
                float* __restrict__ outp,
                float* __restrict__ part) {
    __shared__ unsigned short hs[TM][128];   // bf16 h tile (cols 112..127 zeroed)
    __shared__ float logits[TM][16];         // reused: freq scratch (448 floats) then logits

    const int tid  = threadIdx.x;
    const int lane = tid & 63;
    const int wave = tid >> 6;       // 0..3, owns rows wave*16..+15
    const int r16  = lane & 15;
    const int q    = lane >> 4;      // 0..3

    const float* xp = x + ((size_t)blockIdx.x * TM + wave * 16 + r16) * DIN;
    const unsigned short* wb = wbuf + lane * 8;

    // ---- GEMM1: no LDS, no barriers, no atomics. A prefetched one iter ahead.
    f32x4 acc[7] = {};
    float4 a0, a1;
    {
        const int kk = q * 8;        // t=0 always in range
        a0 = *(const float4*)(xp + kk);
        a1 = *(const float4*)(xp + kk + 4);
    }
    for (int t = 0; t < NT; ++t) {
        float4 n0 = make_float4(0.f, 0.f, 0.f, 0.f), n1 = n0;
        if (t + 1 < NT) {
            const int kk = (t + 1) * 32 + q * 8;
            if (kk < DIN) {          // 784 % 8 == 0 -> never straddles
                n0 = *(const float4*)(xp + kk);
                n1 = *(const float4*)(xp + kk + 4);
            }
        }
        bf16x8 av;
        av[0] = (__bf16)a0.x; av[1] = (__bf16)a0.y;
        av[2] = (__bf16)a0.z; av[3] = (__bf16)a0.w;
        av[4] = (__bf16)a1.x; av[5] = (__bf16)a1.y;
        av[6] = (__bf16)a1.z; av[7] = (__bf16)a1.w;
        const unsigned short* wt = wb + t * (7 * 512);
        #pragma unroll
        for (int n = 0; n < 7; ++n) {
            bf16x8 bv = *(const bf16x8*)(wt + n * 512);
            acc[n] = __builtin_amdgcn_mfma_f32_16x16x32_bf16(av, bv, acc[n], 0, 0, 0);
        }
        a0 = n0; a1 = n1;
    }

    // ---- zero-pad hs k=112..127 (GEMM2 reads them; avoid NaN garbage)
    {
        int r = tid >> 2, cc = (tid & 3) << 2;
        uint2 z; z.x = 0; z.y = 0;
        *(uint2*)&hs[r][112 + cc] = z;
    }

    // ---- bias + relu -> hs (bf16); freq partial from registers (no atomics)
    const bool lastBlk = (blockIdx.x == GRID1 - 1);
    #pragma unroll
    for (int n = 0; n < 7; ++n) {
        const int col = n * 16 + r16;
        const float bias = (col < DHID) ? b1[col] : 0.f;
        float cnt = 0.f;
        #pragma unroll
        for (int i = 0; i < 4; ++i) {
            float v = acc[n][i] + bias;
            v = v > 0.f ? v : 0.f;
            union { __bf16 h; unsigned short u; } cv;
            cv.h = (__bf16)v;
            hs[wave * 16 + q * 4 + i][col] = cv.u;
            // reference skips the globally-last row (65535)
            bool excl = lastBlk && (wave == 3) && (q == 3) && (i == 3);
            cnt += (v > 0.f && !excl) ? 1.f : 0.f;
        }
        cnt += __shfl_xor(cnt, 16);   // reduce over q (lane = q*16 + r16)
        cnt += __shfl_xor(cnt, 32);
        // per-wave partial into logits scratch (disjoint: flat wave*NP+col < 448)
        if (q == 0) ((float*)logits)[wave * NP + col] = cnt;
    }
    __syncthreads();
    // sum 4 per-wave partials -> global partial (non-atomic)
    if (tid < NP) {
        float s = ((float*)logits)[0 * NP + tid] + ((float*)logits)[1 * NP + tid]
                + ((float*)logits)[2 * NP + tid] + ((float*)logits)[3 * NP + tid];
        part[(size_t)blockIdx.x * NP + tid] = s;
    }
    __syncthreads();   // logits scratch free before GEMM2 reuses it

    // ---- GEMM2 via MFMA: logits[64][16] = hs[64][128] @ w2t^T, K=128
    f32x4 acc2 = {};
    const unsigned short* w2t = wbuf + W2T_OFF;
    #pragma unroll
    for (int ks = 0; ks < 4; ++ks) {
        bf16x8 a2  = *(const bf16x8*)&hs[wave * 16 + r16][ks * 32 + q * 8];
        bf16x8 bv2 = *(const bf16x8*)(w2t + r16 * 128 + ks * 32 + q * 8);
        acc2 = __builtin_amdgcn_mfma_f32_16x16x32_bf16(a2, bv2, acc2, 0, 0, 0);
    }
    const float bias2 = (r16 < DOUT) ? b2[r16] : 0.f;
    #pragma unroll
    for (int i = 0; i < 4; ++i)
        logits[wave * 16 + q * 4 + i][r16] = acc2[i] + bias2;
    __syncthreads();

    // ---- softmax: one thread per row
    if (tid < TM) {
        float lg[DOUT];
        #pragma unroll
        for (int k = 0; k < DOUT; ++k) lg[k] = logits[tid][k];
        float mx = lg[0];
        #pragma unroll
        for (int k = 1; k < DOUT; ++k) mx = fmaxf(mx, lg[k]);
        float s = 0.f;
        #pragma unroll
        for (int k = 0; k < DOUT; ++k) { lg[k] = __expf(lg[k] - mx); s += lg[k]; }
        float inv = 1.f / s;
        float* o = outp + ((size_t)blockIdx.x * TM + tid) * DOUT;
        #pragma unroll
        for (int k = 0; k < DOUT; ++k) o[k] = lg[k] * inv;
    }
}

// ---- final freq reduction: freq_out[j] = freq_in[j] + sum_b part[b][j]
__global__ void freq_reduce(const float* __restrict__ part,
                            const float* __restrict__ freq_in,
                            float* __restrict__ freq_out) {
    __shared__ float ws[4];
    const int j = blockIdx.x;        // 0..DHID-1
    const int tid = threadIdx.x;
    float s = 0.f;
    for (int b = tid; b < GRID1; b += 256) s += part[(size_t)b * NP + j];
    #pragma unroll
    for (int d = 1; d < 64; d <<= 1) s += __shfl_xor(s, d);
    if ((tid & 63) == 0) ws[tid >> 6] = s;
    __syncthreads();
    if (tid == 0) freq_out[j] = freq_in[j] + ws[0] + ws[1] + ws[2] + ws[3];
}

extern "C" void kernel_launch(void* const* d_in, const int* in_sizes, int n_in,
                              void* d_out, int out_size, void* d_ws, size_t ws_size,
                              hipStream_t stream) {
    const float* x    = (const float*)d_in[0];
    const float* W1   = (const float*)d_in[1];
    const float* b1   = (const float*)d_in[2];
    const float* freq = (const float*)d_in[3];
    const float* W2   = (const float*)d_in[4];
    const float* b2   = (const float*)d_in[5];
    float* outp     = (float*)d_out;
    float* freq_out = outp + (size_t)B_ROWS * DOUT;
    unsigned short* wbuf = (unsigned short*)d_ws;
    float* part = (float*)((char*)d_ws + PART_OFF);   // 1024*112*4 = 458 KB

    prep_kernel<<<(WBUF_ELEMS + 255) / 256, 256, 0, stream>>>(W1, W2, wbuf);
    fused_mlp3<<<GRID1, 256, 0, stream>>>(x, wbuf, b1, b2, outp, part);
    freq_reduce<<<DHID, 256, 0, stream>>>(part, freq, freq_out);
}

// Round 5
// 55.229 us; speedup vs baseline: 1.5254x; 1.0618x over previous
//
#include <hip/hip_runtime.h>
#include <hip/hip_bf16.h>

// Problem constants
#define B_ROWS 65536
#define DIN    784
#define DHID   100
#define DOUT   10

#define NP     112                 // DHID padded to 7*16
#define NT     25                  // k-steps of 32 (800 >= 784)
#define W1T_ELEMS (NT * 7 * 512)   // 89600 bf16, fragment-order layout
#define W2T_OFF   W1T_ELEMS        // w2t: [16][128] bf16 = 2048
#define WBUF_ELEMS (W1T_ELEMS + 2048)
#define PART_OFF  ((((WBUF_ELEMS * 2) + 255) & ~255))   // byte offset of freq partials
#define TM     128                 // rows per block (4 waves x 32 rows)
#define GRID1  (B_ROWS / TM)       // 512 -> 2 blocks/CU

typedef float  f32x4  __attribute__((ext_vector_type(4)));
typedef __bf16 bf16x8 __attribute__((ext_vector_type(8)));

__device__ inline unsigned short f2bf(float f) {
    unsigned int u = __builtin_bit_cast(unsigned int, f);
    u = (u + 0x7fffu + ((u >> 16) & 1u)) >> 16;   // RNE
    return (unsigned short)u;
}

// ---- prep: build fragment-order W1T + W2T (bf16, zero-padded).
// W1T: idx = ((t*7+n)*64 + lane)*8 + j holds W1[k = t*32+(lane>>4)*8+j][col = n*16+(lane&15)]
// -> B-fragment load = wbuf + t*3584 + n*512 + lane*8, fully coalesced.
__global__ void prep_kernel(const float* __restrict__ W1,
                            const float* __restrict__ W2,
                            unsigned short* __restrict__ wbuf) {
    int idx = blockIdx.x * 256 + threadIdx.x;
    if (idx < W1T_ELEMS) {
        int s  = idx >> 9;          // fragment slot (t*7+n)
        int e  = idx & 511;
        int ln = e >> 3, j = e & 7;
        int n  = s % 7, t = s / 7;
        int k   = t * 32 + ((ln >> 4) << 3) + j;
        int col = n * 16 + (ln & 15);
        float v = (k < DIN && col < DHID) ? W1[k * DHID + col] : 0.f;
        wbuf[idx] = f2bf(v);
    } else if (idx < WBUF_ELEMS) {
        int j2 = idx - W1T_ELEMS;
        int r  = j2 >> 7;           // 0..15 (output col)
        int k  = j2 & 127;          // 0..127 (h col)
        float v = (r < DOUT && k < DHID) ? W2[k * DOUT + r] : 0.f;
        wbuf[idx] = f2bf(v);
    }
}

__global__ __launch_bounds__(256, 2)
void fused_mlp4(const float* __restrict__ x,
                const unsigned short* __restrict__ wbuf,
                const float* __restrict__ b1,
                const float* __restrict__ b2,
                float* __restrict__ outp,
                float* __restrict__ part) {
    __shared__ unsigned short hs[TM][128];   // bf16 h tile (cols 112..127 zeroed)
    __shared__ float logits[TM][16];         // reused: freq scratch (448 f) then logits

    const int tid  = threadIdx.x;
    const int lane = tid & 63;
    const int wave = tid >> 6;       // 0..3, owns rows wave*32 .. +31
    const int r16  = lane & 15;
    const int q    = lane >> 4;      // 0..3

    const float* xp0 = x + ((size_t)blockIdx.x * TM + wave * 32 + r16) * DIN;
    const float* xp1 = xp0 + 16 * DIN;
    const unsigned short* wb = wbuf + lane * 8;

    // ---- GEMM1: no LDS/barriers/atomics. Both A (x) and B (W1T) prefetched
    // one iteration ahead into registers -> loads overlap the 14 MFMAs.
    f32x4 acc[2][7] = {};
    float4 xc[2][2];
    bf16x8 bc[7];
    {
        const int kk = q * 8;
        xc[0][0] = *(const float4*)(xp0 + kk); xc[0][1] = *(const float4*)(xp0 + kk + 4);
        xc[1][0] = *(const float4*)(xp1 + kk); xc[1][1] = *(const float4*)(xp1 + kk + 4);
        #pragma unroll
        for (int n = 0; n < 7; ++n) bc[n] = *(const bf16x8*)(wb + n * 512);
    }
    for (int t = 0; t < NT; ++t) {
        const int tn = (t + 1 < NT) ? t + 1 : NT - 1;   // redundant reload on last iter
        const int kk = tn * 32 + q * 8;
        float4 xn[2][2];
        #pragma unroll
        for (int m = 0; m < 2; ++m)
            #pragma unroll
            for (int hhalf = 0; hhalf < 2; ++hhalf)
                xn[m][hhalf] = make_float4(0.f, 0.f, 0.f, 0.f);
        if (kk < DIN) {
            xn[0][0] = *(const float4*)(xp0 + kk); xn[0][1] = *(const float4*)(xp0 + kk + 4);
            xn[1][0] = *(const float4*)(xp1 + kk); xn[1][1] = *(const float4*)(xp1 + kk + 4);
        }
        const unsigned short* wn = wb + tn * (7 * 512);
        bf16x8 bn[7];
        #pragma unroll
        for (int n = 0; n < 7; ++n) bn[n] = *(const bf16x8*)(wn + n * 512);

        // convert current x -> bf16 fragments, run 14 MFMAs on current B
        bf16x8 av[2];
        #pragma unroll
        for (int m = 0; m < 2; ++m) {
            av[m][0] = (__bf16)xc[m][0].x; av[m][1] = (__bf16)xc[m][0].y;
            av[m][2] = (__bf16)xc[m][0].z; av[m][3] = (__bf16)xc[m][0].w;
            av[m][4] = (__bf16)xc[m][1].x; av[m][5] = (__bf16)xc[m][1].y;
            av[m][6] = (__bf16)xc[m][1].z; av[m][7] = (__bf16)xc[m][1].w;
        }
        #pragma unroll
        for (int n = 0; n < 7; ++n)
            #pragma unroll
            for (int m = 0; m < 2; ++m)
                acc[m][n] = __builtin_amdgcn_mfma_f32_16x16x32_bf16(av[m], bc[n], acc[m][n], 0, 0, 0);

        #pragma unroll
        for (int m = 0; m < 2; ++m) { xc[m][0] = xn[m][0]; xc[m][1] = xn[m][1]; }
        #pragma unroll
        for (int n = 0; n < 7; ++n) bc[n] = bn[n];
    }

    // ---- zero-pad hs cols 112..127 (GEMM2 reads them; avoid NaN garbage)
    {
        int r = tid >> 1, cc = (tid & 1) << 3;        // 16 B per thread
        uint4 z; z.x = z.y = z.z = z.w = 0;
        *(uint4*)&hs[r][112 + cc] = z;
    }

    // ---- bias + relu -> hs (bf16); freq partial from registers (no atomics)
    const bool lastBlk = (blockIdx.x == GRID1 - 1);
    #pragma unroll
    for (int n = 0; n < 7; ++n) {
        const int col = n * 16 + r16;
        const float bias = (col < DHID) ? b1[col] : 0.f;
        float cnt = 0.f;
        #pragma unroll
        for (int m = 0; m < 2; ++m)
            #pragma unroll
            for (int i = 0; i < 4; ++i) {
                float v = acc[m][n][i] + bias;
                v = v > 0.f ? v : 0.f;
                union { __bf16 h; unsigned short u; } cv;
                cv.h = (__bf16)v;
                hs[wave * 32 + m * 16 + q * 4 + i][col] = cv.u;
                // reference skips the globally-last row (65535)
                bool excl = lastBlk && (wave == 3) && (m == 1) && (q == 3) && (i == 3);
                cnt += (v > 0.f && !excl) ? 1.f : 0.f;
            }
        cnt += __shfl_xor(cnt, 16);   // reduce over q (lane = q*16 + r16)
        cnt += __shfl_xor(cnt, 32);
        if (q == 0) ((float*)logits)[wave * NP + col] = cnt;  // flat < 448, disjoint
    }
    __syncthreads();
    if (tid < NP) {
        float s = ((float*)logits)[0 * NP + tid] + ((float*)logits)[1 * NP + tid]
                + ((float*)logits)[2 * NP + tid] + ((float*)logits)[3 * NP + tid];
        part[(size_t)blockIdx.x * NP + tid] = s;
    }
    __syncthreads();   // logits scratch free before GEMM2 reuses it

    // ---- GEMM2 via MFMA: logits[128][16] = hs[128][128] @ w2t^T, K=128
    const unsigned short* w2t = wbuf + W2T_OFF;
    bf16x8 bv2[4];
    #pragma unroll
    for (int ks = 0; ks < 4; ++ks)
        bv2[ks] = *(const bf16x8*)(w2t + r16 * 128 + ks * 32 + q * 8);
    f32x4 acc2[2] = {};
    #pragma unroll
    for (int m = 0; m < 2; ++m)
        #pragma unroll
        for (int ks = 0; ks < 4; ++ks) {
            bf16x8 a2 = *(const bf16x8*)&hs[wave * 32 + m * 16 + r16][ks * 32 + q * 8];
            acc2[m] = __builtin_amdgcn_mfma_f32_16x16x32_bf16(a2, bv2[ks], acc2[m], 0, 0, 0);
        }
    const float bias2 = (r16 < DOUT) ? b2[r16] : 0.f;
    #pragma unroll
    for (int m = 0; m < 2; ++m)
        #pragma unroll
        for (int i = 0; i < 4; ++i)
            logits[wave * 32 + m * 16 + q * 4 + i][r16] = acc2[m][i] + bias2;
    __syncthreads();

    // ---- softmax: one thread per row
    if (tid < TM) {
        float lg[DOUT];
        #pragma unroll
        for (int k = 0; k < DOUT; ++k) lg[k] = logits[tid][k];
        float mx = lg[0];
        #pragma unroll
        for (int k = 1; k < DOUT; ++k) mx = fmaxf(mx, lg[k]);
        float s = 0.f;
        #pragma unroll
        for (int k = 0; k < DOUT; ++k) { lg[k] = __expf(lg[k] - mx); s += lg[k]; }
        float inv = 1.f / s;
        float* o = outp + ((size_t)blockIdx.x * TM + tid) * DOUT;
        #pragma unroll
        for (int k = 0; k < DOUT; ++k) o[k] = lg[k] * inv;
    }
}

// ---- final freq reduction: freq_out[j] = freq_in[j] + sum_b part[b][j]
__global__ void freq_reduce(const float* __restrict__ part,
                            const float* __restrict__ freq_in,
                            float* __restrict__ freq_out) {
    __shared__ float ws[4];
    const int j = blockIdx.x;        // 0..DHID-1
    const int tid = threadIdx.x;
    float s = 0.f;
    for (int b = tid; b < GRID1; b += 256) s += part[(size_t)b * NP + j];
    #pragma unroll
    for (int d = 1; d < 64; d <<= 1) s += __shfl_xor(s, d);
    if ((tid & 63) == 0) ws[tid >> 6] = s;
    __syncthreads();
    if (tid == 0) freq_out[j] = freq_in[j] + ws[0] + ws[1] + ws[2] + ws[3];
}

extern "C" void kernel_launch(void* const* d_in, const int* in_sizes, int n_in,
                              void* d_out, int out_size, void* d_ws, size_t ws_size,
                              hipStream_t stream) {
    const float* x    = (const float*)d_in[0];
    const float* W1   = (const float*)d_in[1];
    const float* b1   = (const float*)d_in[2];
    const float* freq = (const float*)d_in[3];
    const float* W2   = (const float*)d_in[4];
    const float* b2   = (const float*)d_in[5];
    float* outp     = (float*)d_out;
    float* freq_out = outp + (size_t)B_ROWS * DOUT;
    unsigned short* wbuf = (unsigned short*)d_ws;
    float* part = (float*)((char*)d_ws + PART_OFF);   // 512*112*4 = 229 KB

    prep_kernel<<<(WBUF_ELEMS + 255) / 256, 256, 0, stream>>>(W1, W2, wbuf);
    fused_mlp4<<<GRID1, 256, 0, stream>>>(x, wbuf, b1, b2, outp, part);
    freq_reduce<<<DHID, 256, 0, stream>>>(part, freq, freq_out);
}

// Round 6
// 50.346 us; speedup vs baseline: 1.6733x; 1.0970x over previous
//
#include <hip/hip_runtime.h>
#include <hip/hip_bf16.h>

// Problem constants
#define B_ROWS 65536
#define DIN    784
#define DHID   100
#define DOUT   10

#define NP     112                 // DHID padded to 7*16
#define NT     26                  // k-steps of 32 (832; slots 784.. are zero pad)
#define W1T_ELEMS (NT * 7 * 512)   // 93184 bf16, fragment-order layout
#define W2T_OFF   W1T_ELEMS        // w2t: [16][128] bf16 = 2048
#define WBUF_ELEMS (W1T_ELEMS + 2048)
#define PART_OFF  ((((WBUF_ELEMS * 2) + 255) & ~255))   // byte offset of freq partials
#define TM     128                 // rows per block (4 waves x 32 rows)
#define GRID1  (B_ROWS / TM)       // 512 -> 2 blocks/CU

typedef float  f32x4  __attribute__((ext_vector_type(4)));
typedef __bf16 bf16x8 __attribute__((ext_vector_type(8)));

__device__ inline unsigned short f2bf(float f) {
    unsigned int u = __builtin_bit_cast(unsigned int, f);
    u = (u + 0x7fffu + ((u >> 16) & 1u)) >> 16;   // RNE
    return (unsigned short)u;
}

// ---- prep: build fragment-order W1T + W2T (bf16, zero-padded).
// W1T: idx = ((t*7+n)*64 + lane)*8 + j holds W1[k = t*32+(lane>>4)*8+j][col = n*16+(lane&15)]
// -> B-fragment load = wbuf + t*3584 + n*512 + lane*8, fully coalesced.
__global__ void prep_kernel(const float* __restrict__ W1,
                            const float* __restrict__ W2,
                            unsigned short* __restrict__ wbuf) {
    int idx = blockIdx.x * 256 + threadIdx.x;
    if (idx < W1T_ELEMS) {
        int s  = idx >> 9;          // fragment slot (t*7+n)
        int e  = idx & 511;
        int ln = e >> 3, j = e & 7;
        int n  = s % 7, t = s / 7;
        int k   = t * 32 + ((ln >> 4) << 3) + j;
        int col = n * 16 + (ln & 15);
        float v = (k < DIN && col < DHID) ? W1[k * DHID + col] : 0.f;
        wbuf[idx] = f2bf(v);
    } else if (idx < WBUF_ELEMS) {
        int j2 = idx - W1T_ELEMS;
        int r  = j2 >> 7;           // 0..15 (output col)
        int k  = j2 & 127;          // 0..127 (h col)
        float v = (r < DOUT && k < DHID) ? W2[k * DOUT + r] : 0.f;
        wbuf[idx] = f2bf(v);
    }
}

#define LOADX(dst, kk)                                                          \
    do {                                                                        \
        dst[0][0] = *(const float4*)(xp0 + (kk));                               \
        dst[0][1] = *(const float4*)(xp0 + (kk) + 4);                           \
        dst[1][0] = *(const float4*)(xp1 + (kk));                               \
        dst[1][1] = *(const float4*)(xp1 + (kk) + 4);                           \
    } while (0)

#define ZEROX(dst)                                                              \
    do {                                                                        \
        dst[0][0] = dst[0][1] = dst[1][0] = dst[1][1] =                         \
            make_float4(0.f, 0.f, 0.f, 0.f);                                    \
    } while (0)

#define CVT_MFMA(xc, bsrc)                                                      \
    do {                                                                        \
        bf16x8 av[2];                                                           \
        _Pragma("unroll")                                                       \
        for (int m = 0; m < 2; ++m) {                                           \
            av[m][0] = (__bf16)xc[m][0].x; av[m][1] = (__bf16)xc[m][0].y;       \
            av[m][2] = (__bf16)xc[m][0].z; av[m][3] = (__bf16)xc[m][0].w;       \
            av[m][4] = (__bf16)xc[m][1].x; av[m][5] = (__bf16)xc[m][1].y;       \
            av[m][6] = (__bf16)xc[m][1].z; av[m][7] = (__bf16)xc[m][1].w;       \
        }                                                                       \
        _Pragma("unroll")                                                       \
        for (int n = 0; n < 7; ++n)                                             \
            _Pragma("unroll")                                                   \
            for (int m = 0; m < 2; ++m)                                         \
                acc[m][n] = __builtin_amdgcn_mfma_f32_16x16x32_bf16(            \
                    av[m], bsrc[n], acc[m][n], 0, 0, 0);                        \
    } while (0)

__global__ __launch_bounds__(256, 2)
void fused_mlp5(const float* __restrict__ x,
                const unsigned short* __restrict__ wbuf,
                const float* __restrict__ b1,
                const float* __restrict__ b2,
                float* __restrict__ outp,
                float* __restrict__ part) {
    __shared__ unsigned short hs[TM][128];   // bf16 h tile (cols 112..127 zeroed)
    __shared__ float logits[TM][16];         // reused: freq scratch (448 f) then logits

    const int tid  = threadIdx.x;
    const int lane = tid & 63;
    const int wave = tid >> 6;       // 0..3, owns rows wave*32 .. +31
    const int r16  = lane & 15;
    const int q    = lane >> 4;      // 0..3

    const float* xp0 = x + ((size_t)blockIdx.x * TM + wave * 32 + r16) * DIN;
    const float* xp1 = xp0 + 16 * DIN;
    const unsigned short* wb = wbuf + lane * 8;

    // ---- GEMM1: no LDS/barriers/atomics. x pipelined 2 deep, B 1 deep.
    f32x4 acc[2][7] = {};
    float4 xc0[2][2], xc1[2][2];     // stages t, t+1
    bf16x8 bc[7];
    {
        LOADX(xc0, q * 8);           // t=0 (all in range)
        LOADX(xc1, 32 + q * 8);      // t=1
        #pragma unroll
        for (int n = 0; n < 7; ++n) bc[n] = *(const bf16x8*)(wb + n * 512);
    }
    #pragma unroll 1
    for (int tt = 0; tt < NT / 2; ++tt) {
        const int t = tt * 2;
        // ---- phase A (iter t): prefetch x[t+2], B[t+1]; compute xc0 x bc
        float4 xn0[2][2];
        const int kkA = (t + 2) * 32 + q * 8;
        if (kkA + 8 <= DIN) LOADX(xn0, kkA); else ZEROX(xn0);
        const unsigned short* wA = wb + (t + 1) * (7 * 512);
        bf16x8 bn[7];
        #pragma unroll
        for (int n = 0; n < 7; ++n) bn[n] = *(const bf16x8*)(wA + n * 512);
        CVT_MFMA(xc0, bc);

        // ---- phase B (iter t+1): prefetch x[t+3], B[t+2]; compute xc1 x bn
        float4 xn1[2][2];
        const int kkB = (t + 3) * 32 + q * 8;
        if (kkB + 8 <= DIN) LOADX(xn1, kkB); else ZEROX(xn1);
        const int tb2 = (t + 2 < NT) ? (t + 2) : (NT - 1);
        const unsigned short* wB = wb + tb2 * (7 * 512);
        #pragma unroll
        for (int n = 0; n < 7; ++n) bc[n] = *(const bf16x8*)(wB + n * 512);
        CVT_MFMA(xc1, bn);

        // rotate x stages
        #pragma unroll
        for (int m = 0; m < 2; ++m) {
            xc0[m][0] = xn0[m][0]; xc0[m][1] = xn0[m][1];
            xc1[m][0] = xn1[m][0]; xc1[m][1] = xn1[m][1];
        }
    }

    // ---- zero-pad hs cols 112..127 (GEMM2 reads them; avoid NaN garbage)
    {
        int r = tid >> 1, cc = (tid & 1) << 3;        // 16 B per thread
        uint4 z; z.x = z.y = z.z = z.w = 0;
        *(uint4*)&hs[r][112 + cc] = z;
    }

    // ---- bias + relu -> hs (bf16); freq partial from registers (no atomics)
    const bool lastBlk = (blockIdx.x == GRID1 - 1);
    #pragma unroll
    for (int n = 0; n < 7; ++n) {
        const int col = n * 16 + r16;
        const float bias = (col < DHID) ? b1[col] : 0.f;
        float cnt = 0.f;
        #pragma unroll
        for (int m = 0; m < 2; ++m)
            #pragma unroll
            for (int i = 0; i < 4; ++i) {
                float v = acc[m][n][i] + bias;
                v = v > 0.f ? v : 0.f;
                union { __bf16 h; unsigned short u; } cv;
                cv.h = (__bf16)v;
                hs[wave * 32 + m * 16 + q * 4 + i][col] = cv.u;
                // reference skips the globally-last row (65535)
                bool excl = lastBlk && (wave == 3) && (m == 1) && (q == 3) && (i == 3);
                cnt += (v > 0.f && !excl) ? 1.f : 0.f;
            }
        cnt += __shfl_xor(cnt, 16);   // reduce over q (lane = q*16 + r16)
        cnt += __shfl_xor(cnt, 32);
        if (q == 0) ((float*)logits)[wave * NP + col] = cnt;  // flat < 448, disjoint
    }
    __syncthreads();
    if (tid < NP) {
        float s = ((float*)logits)[0 * NP + tid] + ((float*)logits)[1 * NP + tid]
                + ((float*)logits)[2 * NP + tid] + ((float*)logits)[3 * NP + tid];
        part[(size_t)blockIdx.x * NP + tid] = s;
    }
    __syncthreads();   // logits scratch free before GEMM2 reuses it

    // ---- GEMM2 via MFMA: logits[128][16] = hs[128][128] @ w2t^T, K=128
    const unsigned short* w2t = wbuf + W2T_OFF;
    bf16x8 bv2[4];
    #pragma unroll
    for (int ks = 0; ks < 4; ++ks)
        bv2[ks] = *(const bf16x8*)(w2t + r16 * 128 + ks * 32 + q * 8);
    f32x4 acc2[2] = {};
    #pragma unroll
    for (int m = 0; m < 2; ++m)
        #pragma unroll
        for (int ks = 0; ks < 4; ++ks) {
            bf16x8 a2 = *(const bf16x8*)&hs[wave * 32 + m * 16 + r16][ks * 32 + q * 8];
            acc2[m] = __builtin_amdgcn_mfma_f32_16x16x32_bf16(a2, bv2[ks], acc2[m], 0, 0, 0);
        }
    const float bias2 = (r16 < DOUT) ? b2[r16] : 0.f;
    #pragma unroll
    for (int m = 0; m < 2; ++m)
        #pragma unroll
        for (int i = 0; i < 4; ++i)
            logits[wave * 32 + m * 16 + q * 4 + i][r16] = acc2[m][i] + bias2;
    __syncthreads();

    // ---- softmax: one thread per row
    if (tid < TM) {
        float lg[DOUT];
        #pragma unroll
        for (int k = 0; k < DOUT; ++k) lg[k] = logits[tid][k];
        float mx = lg[0];
        #pragma unroll
        for (int k = 1; k < DOUT; ++k) mx = fmaxf(mx, lg[k]);
        float s = 0.f;
        #pragma unroll
        for (int k = 0; k < DOUT; ++k) { lg[k] = __expf(lg[k] - mx); s += lg[k]; }
        float inv = 1.f / s;
        float* o = outp + ((size_t)blockIdx.x * TM + tid) * DOUT;
        #pragma unroll
        for (int k = 0; k < DOUT; ++k) o[k] = lg[k] * inv;
    }
}

// ---- final freq reduction: freq_out[j] = freq_in[j] + sum_b part[b][j]
__global__ void freq_reduce(const float* __restrict__ part,
                            const float* __restrict__ freq_in,
                            float* __restrict__ freq_out) {
    __shared__ float ws[4];
    const int j = blockIdx.x;        // 0..DHID-1
    const int tid = threadIdx.x;
    float s = 0.f;
    for (int b = tid; b < GRID1; b += 256) s += part[(size_t)b * NP + j];
    #pragma unroll
    for (int d = 1; d < 64; d <<= 1) s += __shfl_xor(s, d);
    if ((tid & 63) == 0) ws[tid >> 6] = s;
    __syncthreads();
    if (tid == 0) freq_out[j] = freq_in[j] + ws[0] + ws[1] + ws[2] + ws[3];
}

extern "C" void kernel_launch(void* const* d_in, const int* in_sizes, int n_in,
                              void* d_out, int out_size, void* d_ws, size_t ws_size,
                              hipStream_t stream) {
    const float* x    = (const float*)d_in[0];
    const float* W1   = (const float*)d_in[1];
    const float* b1   = (const float*)d_in[2];
    const float* freq = (const float*)d_in[3];
    const float* W2   = (const float*)d_in[4];
    const float* b2   = (const float*)d_in[5];
    float* outp     = (float*)d_out;
    float* freq_out = outp + (size_t)B_ROWS * DOUT;
    unsigned short* wbuf = (unsigned short*)d_ws;
    float* part = (float*)((char*)d_ws + PART_OFF);   // 512*112*4 = 229 KB

    prep_kernel<<<(WBUF_ELEMS + 255) / 256, 256, 0, stream>>>(W1, W2, wbuf);
    fused_mlp5<<<GRID1, 256, 0, stream>>>(x, wbuf, b1, b2, outp, part);
    freq_reduce<<<DHID, 256, 0, stream>>>(part, freq, freq_out);
}

// Round 7
// 48.383 us; speedup vs baseline: 1.7412x; 1.0406x over previous
//
#include <hip/hip_runtime.h>
#include <hip/hip_bf16.h>

// Problem constants
#define B_ROWS 65536
#define DIN    784
#define DHID   100
#define DOUT   10

#define NP     112                 // DHID padded to 7*16
#define NT     26                  // k-steps of 32 (832; slots 784.. are zero pad)
#define W1T_ELEMS (NT * 7 * 512)   // 93184 bf16, fragment-order layout
#define W2T_OFF   W1T_ELEMS        // w2t: [16][128] bf16 = 2048
#define WBUF_ELEMS (W1T_ELEMS + 2048)
#define PART_OFF  ((((WBUF_ELEMS * 2) + 255) & ~255))   // byte offset of freq partials
#define TM     256                 // rows per block (4 waves x 64 rows)
#define GRID1  (B_ROWS / TM)       // 256 -> 1 block/CU, 1 wave/SIMD

typedef float  f32x4  __attribute__((ext_vector_type(4)));
typedef __bf16 bf16x8 __attribute__((ext_vector_type(8)));

__device__ inline unsigned short f2bf(float f) {
    unsigned int u = __builtin_bit_cast(unsigned int, f);
    u = (u + 0x7fffu + ((u >> 16) & 1u)) >> 16;   // RNE
    return (unsigned short)u;
}

// ---- prep: build fragment-order W1T + W2T (bf16, zero-padded).
// W1T: idx = ((t*7+n)*64 + lane)*8 + j holds W1[k = t*32+(lane>>4)*8+j][col = n*16+(lane&15)]
// -> B-fragment load = wbuf + t*3584 + n*512 + lane*8, fully coalesced.
__global__ void prep_kernel(const float* __restrict__ W1,
                            const float* __restrict__ W2,
                            unsigned short* __restrict__ wbuf) {
    int idx = blockIdx.x * 256 + threadIdx.x;
    if (idx < W1T_ELEMS) {
        int s  = idx >> 9;          // fragment slot (t*7+n)
        int e  = idx & 511;
        int ln = e >> 3, j = e & 7;
        int n  = s % 7, t = s / 7;
        int k   = t * 32 + ((ln >> 4) << 3) + j;
        int col = n * 16 + (ln & 15);
        float v = (k < DIN && col < DHID) ? W1[k * DHID + col] : 0.f;
        wbuf[idx] = f2bf(v);
    } else if (idx < WBUF_ELEMS) {
        int j2 = idx - W1T_ELEMS;
        int r  = j2 >> 7;           // 0..15 (output col)
        int k  = j2 & 127;          // 0..127 (h col)
        float v = (r < DOUT && k < DHID) ? W2[k * DOUT + r] : 0.f;
        wbuf[idx] = f2bf(v);
    }
}

#define LOADX4(dst, kk)                                                         \
    do {                                                                        \
        _Pragma("unroll")                                                       \
        for (int m = 0; m < 4; ++m) {                                           \
            dst[m][0] = *(const float4*)(xp[m] + (kk));                         \
            dst[m][1] = *(const float4*)(xp[m] + (kk) + 4);                     \
        }                                                                       \
    } while (0)

#define ZEROX4(dst)                                                             \
    do {                                                                        \
        _Pragma("unroll")                                                       \
        for (int m = 0; m < 4; ++m)                                             \
            dst[m][0] = dst[m][1] = make_float4(0.f, 0.f, 0.f, 0.f);            \
    } while (0)

#define CVT_MFMA4(xc, bsrc)                                                     \
    do {                                                                        \
        bf16x8 av[4];                                                           \
        _Pragma("unroll")                                                       \
        for (int m = 0; m < 4; ++m) {                                           \
            av[m][0] = (__bf16)xc[m][0].x; av[m][1] = (__bf16)xc[m][0].y;       \
            av[m][2] = (__bf16)xc[m][0].z; av[m][3] = (__bf16)xc[m][0].w;       \
            av[m][4] = (__bf16)xc[m][1].x; av[m][5] = (__bf16)xc[m][1].y;       \
            av[m][6] = (__bf16)xc[m][1].z; av[m][7] = (__bf16)xc[m][1].w;       \
        }                                                                       \
        _Pragma("unroll")                                                       \
        for (int n = 0; n < 7; ++n)                                             \
            _Pragma("unroll")                                                   \
            for (int m = 0; m < 4; ++m)                                         \
                acc[m][n] = __builtin_amdgcn_mfma_f32_16x16x32_bf16(            \
                    av[m], bsrc[n], acc[m][n], 0, 0, 0);                        \
    } while (0)

__global__ __launch_bounds__(256, 1)
void fused_mlp6(const float* __restrict__ x,
                const unsigned short* __restrict__ wbuf,
                const float* __restrict__ b1,
                const float* __restrict__ b2,
                float* __restrict__ outp,
                float* __restrict__ part) {
    __shared__ unsigned short hs[TM][128];   // 64 KB bf16 h tile (cols 112..127 zeroed)
    __shared__ float logits[TM][16];         // 16 KB; reused: freq scratch then logits

    const int tid  = threadIdx.x;
    const int lane = tid & 63;
    const int wave = tid >> 6;       // 0..3, owns rows wave*64 .. +63
    const int r16  = lane & 15;
    const int q    = lane >> 4;      // 0..3

    const float* xp[4];
    #pragma unroll
    for (int m = 0; m < 4; ++m)
        xp[m] = x + ((size_t)blockIdx.x * TM + wave * 64 + m * 16 + r16) * DIN;
    const unsigned short* wb = wbuf + lane * 8;

    // ---- GEMM1: 64 rows/wave (4 A-frags share each B-frag), x 2-deep, B 1-deep.
    f32x4 acc[4][7] = {};
    float4 xc0[4][2], xc1[4][2];     // stages t, t+1
    bf16x8 bc[7];
    {
        LOADX4(xc0, q * 8);          // t=0 (all in range)
        LOADX4(xc1, 32 + q * 8);     // t=1
        #pragma unroll
        for (int n = 0; n < 7; ++n) bc[n] = *(const bf16x8*)(wb + n * 512);
    }
    #pragma unroll 1
    for (int tt = 0; tt < NT / 2; ++tt) {
        const int t = tt * 2;
        // ---- phase A (iter t): prefetch x[t+2], B[t+1]; compute xc0 x bc
        float4 xn0[4][2];
        const int kkA = (t + 2) * 32 + q * 8;
        if (kkA + 8 <= DIN) LOADX4(xn0, kkA); else ZEROX4(xn0);
        const unsigned short* wA = wb + (t + 1) * (7 * 512);
        bf16x8 bn[7];
        #pragma unroll
        for (int n = 0; n < 7; ++n) bn[n] = *(const bf16x8*)(wA + n * 512);
        CVT_MFMA4(xc0, bc);

        // ---- phase B (iter t+1): prefetch x[t+3], B[t+2]; compute xc1 x bn
        float4 xn1[4][2];
        const int kkB = (t + 3) * 32 + q * 8;
        if (kkB + 8 <= DIN) LOADX4(xn1, kkB); else ZEROX4(xn1);
        const int tb2 = (t + 2 < NT) ? (t + 2) : (NT - 1);
        const unsigned short* wB = wb + tb2 * (7 * 512);
        #pragma unroll
        for (int n = 0; n < 7; ++n) bc[n] = *(const bf16x8*)(wB + n * 512);
        CVT_MFMA4(xc1, bn);

        // rotate x stages
        #pragma unroll
        for (int m = 0; m < 4; ++m) {
            xc0[m][0] = xn0[m][0]; xc0[m][1] = xn0[m][1];
            xc1[m][0] = xn1[m][0]; xc1[m][1] = xn1[m][1];
        }
    }

    // ---- zero-pad hs cols 112..127 (GEMM2 reads them; avoid NaN garbage)
    {
        uint4 z; z.x = z.y = z.z = z.w = 0;
        *(uint4*)&hs[tid][112] = z;
        *(uint4*)&hs[tid][120] = z;
    }

    // ---- bias + relu -> hs (bf16); freq partial from registers (no atomics)
    const bool lastBlk = (blockIdx.x == GRID1 - 1);
    #pragma unroll
    for (int n = 0; n < 7; ++n) {
        const int col = n * 16 + r16;
        const float bias = (col < DHID) ? b1[col] : 0.f;
        float cnt = 0.f;
        #pragma unroll
        for (int m = 0; m < 4; ++m)
            #pragma unroll
            for (int i = 0; i < 4; ++i) {
                float v = acc[m][n][i] + bias;
                v = v > 0.f ? v : 0.f;
                union { __bf16 h; unsigned short u; } cv;
                cv.h = (__bf16)v;
                hs[wave * 64 + m * 16 + q * 4 + i][col] = cv.u;
                // reference skips the globally-last row (65535)
                bool excl = lastBlk && (wave == 3) && (m == 3) && (q == 3) && (i == 3);
                cnt += (v > 0.f && !excl) ? 1.f : 0.f;
            }
        cnt += __shfl_xor(cnt, 16);   // reduce over q (lane = q*16 + r16)
        cnt += __shfl_xor(cnt, 32);
        if (q == 0) ((float*)logits)[wave * NP + col] = cnt;  // flat < 448, disjoint
    }
    __syncthreads();
    if (tid < NP) {
        float s = ((float*)logits)[0 * NP + tid] + ((float*)logits)[1 * NP + tid]
                + ((float*)logits)[2 * NP + tid] + ((float*)logits)[3 * NP + tid];
        part[(size_t)blockIdx.x * NP + tid] = s;
    }
    __syncthreads();   // logits scratch free before GEMM2 reuses it

    // ---- GEMM2 via MFMA: logits[256][16] = hs[256][128] @ w2t^T, K=128
    const unsigned short* w2t = wbuf + W2T_OFF;
    bf16x8 bv2[4];
    #pragma unroll
    for (int ks = 0; ks < 4; ++ks)
        bv2[ks] = *(const bf16x8*)(w2t + r16 * 128 + ks * 32 + q * 8);
    f32x4 acc2[4] = {};
    #pragma unroll
    for (int m = 0; m < 4; ++m)
        #pragma unroll
        for (int ks = 0; ks < 4; ++ks) {
            bf16x8 a2 = *(const bf16x8*)&hs[wave * 64 + m * 16 + r16][ks * 32 + q * 8];
            acc2[m] = __builtin_amdgcn_mfma_f32_16x16x32_bf16(a2, bv2[ks], acc2[m], 0, 0, 0);
        }
    const float bias2 = (r16 < DOUT) ? b2[r16] : 0.f;
    #pragma unroll
    for (int m = 0; m < 4; ++m)
        #pragma unroll
        for (int i = 0; i < 4; ++i)
            logits[wave * 64 + m * 16 + q * 4 + i][r16] = acc2[m][i] + bias2;
    __syncthreads();

    // ---- softmax: one thread per row (all 256 threads active)
    {
        float lg[DOUT];
        #pragma unroll
        for (int k = 0; k < DOUT; ++k) lg[k] = logits[tid][k];
        float mx = lg[0];
        #pragma unroll
        for (int k = 1; k < DOUT; ++k) mx = fmaxf(mx, lg[k]);
        float s = 0.f;
        #pragma unroll
        for (int k = 0; k < DOUT; ++k) { lg[k] = __expf(lg[k] - mx); s += lg[k]; }
        float inv = 1.f / s;
        float* o = outp + ((size_t)blockIdx.x * TM + tid) * DOUT;
        #pragma unroll
        for (int k = 0; k < DOUT; ++k) o[k] = lg[k] * inv;
    }
}

// ---- final freq reduction: freq_out[j] = freq_in[j] + sum_b part[b][j]
__global__ void freq_reduce(const float* __restrict__ part,
                            const float* __restrict__ freq_in,
                            float* __restrict__ freq_out) {
    __shared__ float ws[4];
    const int j = blockIdx.x;        // 0..DHID-1
    const int tid = threadIdx.x;
    float s = 0.f;
    for (int b = tid; b < GRID1; b += 256) s += part[(size_t)b * NP + j];
    #pragma unroll
    for (int d = 1; d < 64; d <<= 1) s += __shfl_xor(s, d);
    if ((tid & 63) == 0) ws[tid >> 6] = s;
    __syncthreads();
    if (tid == 0) freq_out[j] = freq_in[j] + ws[0] + ws[1] + ws[2] + ws[3];
}

extern "C" void kernel_launch(void* const* d_in, const int* in_sizes, int n_in,
                              void* d_out, int out_size, void* d_ws, size_t ws_size,
                              hipStream_t stream) {
    const float* x    = (const float*)d_in[0];
    const float* W1   = (const float*)d_in[1];
    const float* b1   = (const float*)d_in[2];
    const float* freq = (const float*)d_in[3];
    const float* W2   = (const float*)d_in[4];
    const float* b2   = (const float*)d_in[5];
    float* outp     = (float*)d_out;
    float* freq_out = outp + (size_t)B_ROWS * DOUT;
    unsigned short* wbuf = (unsigned short*)d_ws;
    float* part = (float*)((char*)d_ws + PART_OFF);   // 256*112*4 = 115 KB

    prep_kernel<<<(WBUF_ELEMS + 255) / 256, 256, 0, stream>>>(W1, W2, wbuf);
    fused_mlp6<<<GRID1, 256, 0, stream>>>(x, wbuf, b1, b2, outp, part);
    freq_reduce<<<DHID, 256, 0, stream>>>(part, freq, freq_out);
}